// Round 7
// baseline (792.415 us; speedup 1.0000x reference)
//
#include <hip/hip_runtime.h>
#include <stdint.h>

typedef unsigned short u16;
typedef __bf16 bf16x8 __attribute__((ext_vector_type(8)));
typedef float f32x4 __attribute__((ext_vector_type(4)));
typedef int i32x4u __attribute__((ext_vector_type(4), aligned(4)));
typedef int i32x2u __attribute__((ext_vector_type(2), aligned(4)));

#define NNODES 150000
#define KNBR 27
#define LDX 128
#define MR 128     // rows per block; 8 waves x 16 rows, each wave computes g AND h
#define APAD 72    // epilogue LDS row stride (u16)
#define WSU2 16384 // u16 per 32KB window buffer (2 k-steps)
#define NWIN 14    // ceil(27/2) windows

#define WAITVM(N) asm volatile("s_waitcnt vmcnt(" #N ")" ::: "memory")

static __device__ __forceinline__ void gl_lds16(const u16* g, u16* l){
  __builtin_amdgcn_global_load_lds((const __attribute__((address_space(1))) void*)g,
                                   (__attribute__((address_space(3))) void*)l, 16, 0, 0);
}

static __device__ __forceinline__ u16 f2bf(float f){
  union { float f; uint32_t i; } v; v.f = f;
  uint32_t x = v.i;
  uint32_t r = (x + 0x7fffu + ((x >> 16) & 1u)) >> 16;  // RNE
  return (u16)r;
}
static __device__ __forceinline__ float lrelu(float v){ return v >= 0.f ? v : 0.2f*v; }

// fp32 weight (krows x 64) -> bf16 MFMA B-fragment order
__global__ void reformat_w(const float* __restrict__ src, u16* __restrict__ dst, int ksteps){
  int idx = blockIdx.x*256 + threadIdx.x;
  int total = ksteps*4*64;
  if (idx >= total) return;
  int lane = idx & 63;
  int ctile = (idx >> 6) & 3;
  int t = idx >> 8;
  int quad = lane >> 4, m = lane & 15;
  union { u16 h[8]; float4 v; } tmp;
  const float* s = src + ((size_t)(t*32 + quad*8))*64 + ctile*16 + m;
  #pragma unroll
  for (int j=0;j<8;j++) tmp.h[j] = f2bf(s[j*64]);
  *reinterpret_cast<float4*>(dst + (size_t)idx*8) = tmp.v;
}

// x cols 64..127 (fp32, LDX stride) -> bf16 table sb (N x 64)
__global__ void conv_x2(const float* __restrict__ x, u16* __restrict__ sb){
  int idx = blockIdx.x*256 + threadIdx.x;
  int e = idx*8;
  if (e >= NNODES*64) return;
  int row = e >> 6, col = e & 63;
  const float* s = x + (size_t)row*LDX + 64 + col;
  float4 a = *reinterpret_cast<const float4*>(s);
  float4 b = *reinterpret_cast<const float4*>(s+4);
  union { u16 h[8]; float4 v; } t;
  t.h[0]=f2bf(a.x); t.h[1]=f2bf(a.y); t.h[2]=f2bf(a.z); t.h[3]=f2bf(a.w);
  t.h[4]=f2bf(b.x); t.h[5]=f2bf(b.y); t.h[6]=f2bf(b.z); t.h[7]=f2bf(b.w);
  *reinterpret_cast<float4*>(sb + e) = t.v;
}

// Load this lane's 27 neighbor indices into registers (no overread).
#define LOAD_NID(nbrp, rsel) { \
  const int* nr_ = (nbrp) + (size_t)(rsel)*KNBR; \
  _Pragma("unroll") \
  for (int j_=0;j_<6;j_++){ \
    i32x4u v_ = *reinterpret_cast<const i32x4u*>(nr_ + 4*j_); \
    nid[4*j_+0]=v_[0]; nid[4*j_+1]=v_[1]; nid[4*j_+2]=v_[2]; nid[4*j_+3]=v_[3]; \
  } \
  { i32x2u v_ = *reinterpret_cast<const i32x2u*>(nr_ + 24); \
    nid[24]=v_[0]; nid[25]=v_[1]; } \
  nid[26] = nr_[26]; }

// Stage window w_ (k=2w, 2w+1) into ws[w&1]: 32 chunks of 1KB (16 for half window).
// chunk c: ks=c>>4, cc=c&15: mat=(cc>>2)&1, tt=cc>>3, ct=cc&3.
#define STAGE_WIN(w_, wG, wH) { \
  u16* db_ = ws + ((w_)&1)*WSU2; \
  if (2*(w_)+1 < KNBR){ \
    _Pragma("unroll") \
    for (int j_=0;j_<4;j_++){ \
      int c_ = wv*4 + j_; \
      int ks_ = c_>>4, cc_ = c_&15; \
      int mat_=(cc_>>2)&1, tt_=cc_>>3, ct_=cc_&3; \
      const u16* src_ = (mat_? (wH):(wG)) + ((size_t)(2*(2*(w_)+ks_)+tt_))*2048 + (size_t)ct_*512 + (size_t)lane*8; \
      gl_lds16(src_, db_ + (size_t)c_*512); \
    } \
  } else { \
    _Pragma("unroll") \
    for (int j_=0;j_<2;j_++){ \
      int c_ = wv*2 + j_; \
      int mat_=(c_>>2)&1, tt_=c_>>3, ct_=c_&3; \
      const u16* src_ = (mat_? (wH):(wG)) + ((size_t)(2*(2*(w_))+tt_))*2048 + (size_t)ct_*512 + (size_t)lane*8; \
      gl_lds16(src_, db_ + (size_t)c_*512); \
    } \
  } }

// u[:,0:64] = lrelu(lrelu(gather(sb) @ w1g) @ w2g); u[:,64:128] = h-version.
// 8 waves x 16 rows; both matrices per wave. 2-k-step windows, single barrier
// per window, counted vmcnt; indices in registers; weights LDS double-buffered.
// A-loads for window w+2 issued AFTER the MFMAs of window w (slot (w+2)&1==w&1
// is only free once window w's MFMAs consumed it — r6's bug was loading early).
__global__ __launch_bounds__(512,4) void conv1_fused(
    const u16* __restrict__ sb,
    const int* __restrict__ nbr,
    const u16* __restrict__ wb1g, const u16* __restrict__ wb1h,
    const u16* __restrict__ wb2g, const u16* __restrict__ wb2h,
    u16* __restrict__ u)
{
  extern __shared__ char smem[];
  u16* ws  = (u16*)smem;                    // [2][WSU2] = 65536 B
  u16* sa  = (u16*)smem;                    // epilogue alias [2][MR*APAD] = 36864 B
  u16* w2l = (u16*)(smem + 36864);          // epilogue w2 stage = 16384 B

  int tid = threadIdx.x;
  int lane = tid & 63;
  int wv = tid >> 6;                        // 0..7
  int quad = lane >> 4, m = lane & 15;
  int qoff = quad * 8;
  int row0 = blockIdx.x * MR;
  int myrow = row0 + wv*16 + m;
  int rsel = (myrow < NNODES) ? myrow : 0;

  int nid[KNBR];
  LOAD_NID(nbr, rsel);

  f32x4 acc[2][4];
  f32x4 zz = {0.f,0.f,0.f,0.f};
  #pragma unroll
  for (int mt2=0;mt2<2;mt2++)
    #pragma unroll
    for (int i=0;i<4;i++) acc[mt2][i] = zz;

  bf16x8 as1[2][2][2];  // [win&1][ks][khalf]

  #define LOADW1(w_) { \
    { const u16* r_ = sb + (size_t)nid[2*(w_)]*64 + qoff; \
      as1[(w_)&1][0][0] = *reinterpret_cast<const bf16x8*>(r_); \
      as1[(w_)&1][0][1] = *reinterpret_cast<const bf16x8*>(r_ + 32); } \
    if (2*(w_)+1 < KNBR){ \
      const u16* r_ = sb + (size_t)nid[2*(w_)+1]*64 + qoff; \
      as1[(w_)&1][1][0] = *reinterpret_cast<const bf16x8*>(r_); \
      as1[(w_)&1][1][1] = *reinterpret_cast<const bf16x8*>(r_ + 32); } }

  // prologue queue: S0(4), A0(4), A1(4)
  STAGE_WIN(0, wb1g, wb1h); __builtin_amdgcn_sched_barrier(0);
  LOADW1(0); __builtin_amdgcn_sched_barrier(0);
  LOADW1(1);

  #pragma unroll
  for (int w=0; w<NWIN; ++w){
    // queue entering W_w (steady): [A(w)4, S(w)4, A(w+1)4] -> keep newest 4
    if (w < 12)       { WAITVM(4); }
    else if (w == 12) { WAITVM(2); }   // A13 is only 2 loads
    else              { WAITVM(0); }
    __builtin_amdgcn_s_barrier();          // publish S(w); buf[(w+1)&1] free

    if (w+1 < NWIN) { STAGE_WIN(w+1, wb1g, wb1h); }
    __builtin_amdgcn_sched_barrier(0);

    #pragma unroll
    for (int ks=0; ks<2; ks++){
      if (2*w + ks < KNBR){
        const u16* wsb = ws + (w&1)*WSU2 + ks*8192;
        #pragma unroll
        for (int tt=0;tt<2;tt++){
          bf16x8 af = as1[w&1][ks][tt];
          #pragma unroll
          for (int mt2=0;mt2<2;mt2++){
            #pragma unroll
            for (int ct=0;ct<4;ct++){
              bf16x8 b = *reinterpret_cast<const bf16x8*>(wsb + ((tt*2+mt2)*4+ct)*512 + (size_t)lane*8);
              acc[mt2][ct] = __builtin_amdgcn_mfma_f32_16x16x32_bf16(af, b, acc[mt2][ct], 0,0,0);
            }
          }
        }
      }
    }
    // A(w+2) into the slot the MFMAs above just consumed ((w+2)&1 == w&1)
    if (w+2 < NWIN) { LOADW1(w+2); }
  }
  __syncthreads();   // all waves done reading ws before sa/w2l alias

  // stage w2g+w2h (16KB, 16 chunks): wave wv stages chunks 2wv, 2wv+1
  #pragma unroll
  for (int j_=0;j_<2;j_++){
    int cc = wv*2 + j_;
    int mt2_ = cc>>3;                       // 0=g, 1=h
    const u16* src_ = (mt2_ ? wb2h : wb2g) + (size_t)(cc&7)*512 + (size_t)lane*8;
    gl_lds16(src_, w2l + (size_t)cc*512);
  }

  // lrelu -> bf16 tile in LDS (C-layout -> A-layout round trip); wave-private rows
  #pragma unroll
  for (int mt2=0;mt2<2;mt2++){
    #pragma unroll
    for (int ct=0;ct<4;ct++){
      #pragma unroll
      for (int i=0;i<4;i++){
        int rl = wv*16 + quad*4 + i;
        sa[mt2*MR*APAD + rl*APAD + ct*16 + m] = f2bf(lrelu(acc[mt2][ct][i]));
      }
    }
  }
  WAITVM(0);
  __syncthreads();   // w2l staged + sa visible

  f32x4 d[2][4];
  #pragma unroll
  for (int mt2=0;mt2<2;mt2++)
    #pragma unroll
    for (int i=0;i<4;i++) d[mt2][i] = zz;
  #pragma unroll
  for (int c=0;c<2;c++){
    #pragma unroll
    for (int mt2=0;mt2<2;mt2++){
      bf16x8 a = *reinterpret_cast<const bf16x8*>(&sa[mt2*MR*APAD + (wv*16 + m)*APAD + c*32 + qoff]);
      #pragma unroll
      for (int ct=0;ct<4;ct++){
        bf16x8 b = *reinterpret_cast<const bf16x8*>(w2l + (size_t)(mt2*8 + c*4 + ct)*512 + (size_t)lane*8);
        d[mt2][ct] = __builtin_amdgcn_mfma_f32_16x16x32_bf16(a, b, d[mt2][ct], 0,0,0);
      }
    }
  }
  #pragma unroll
  for (int mt2=0;mt2<2;mt2++){
    #pragma unroll
    for (int ct=0;ct<4;ct++){
      #pragma unroll
      for (int i=0;i<4;i++){
        int row = row0 + wv*16 + quad*4 + i;
        if (row < NNODES){
          u[(size_t)row*128 + mt2*64 + ct*16 + m] = f2bf(lrelu(d[mt2][ct][i]));
        }
      }
    }
  }
  #undef LOADW1
}

// bg = gather(u[:,:64]) @ w3g ; bh = gather(u[:,64:]) @ w3h ;
// y = x_prev * exp(2*sigmoid(bg)-1) + bh -> out fp32; optionally y -> yb bf16.
// 8 waves x 16 rows, both matrices per wave; 2-k-step windows, counted vmcnt.
__global__ __launch_bounds__(512,4) void conv2_coupling(
    const u16* __restrict__ ub,
    const int* __restrict__ nbr,
    const u16* __restrict__ wbg, const u16* __restrict__ wbh,
    const float* __restrict__ x, int xcol0,
    float* __restrict__ out, int ycol0,
    u16* __restrict__ yb, int write_yb)
{
  extern __shared__ char smem[];
  u16* ws = (u16*)smem;                     // [2][WSU2] = 65536 B

  int tid = threadIdx.x;
  int lane = tid & 63;
  int wv = tid >> 6;                        // 0..7
  int quad = lane >> 4, m = lane & 15;
  int qoff = quad * 8;
  int row0 = blockIdx.x * MR;
  int myrow = row0 + wv*16 + m;
  int rsel = (myrow < NNODES) ? myrow : 0;

  int nid[KNBR];
  LOAD_NID(nbr, rsel);

  f32x4 accg[4], acch[4];
  f32x4 zz = {0.f,0.f,0.f,0.f};
  #pragma unroll
  for (int i=0;i<4;i++){ accg[i]=zz; acch[i]=zz; }

  bf16x8 as2[2][2][4];  // [win&1][ks][frag: g0,g1,h0,h1]

  #define LOADW2(w_) { \
    { const u16* r_ = ub + (size_t)nid[2*(w_)]*128 + qoff; \
      as2[(w_)&1][0][0] = *reinterpret_cast<const bf16x8*>(r_); \
      as2[(w_)&1][0][1] = *reinterpret_cast<const bf16x8*>(r_ + 32); \
      as2[(w_)&1][0][2] = *reinterpret_cast<const bf16x8*>(r_ + 64); \
      as2[(w_)&1][0][3] = *reinterpret_cast<const bf16x8*>(r_ + 96); } \
    if (2*(w_)+1 < KNBR){ \
      const u16* r_ = ub + (size_t)nid[2*(w_)+1]*128 + qoff; \
      as2[(w_)&1][1][0] = *reinterpret_cast<const bf16x8*>(r_); \
      as2[(w_)&1][1][1] = *reinterpret_cast<const bf16x8*>(r_ + 32); \
      as2[(w_)&1][1][2] = *reinterpret_cast<const bf16x8*>(r_ + 64); \
      as2[(w_)&1][1][3] = *reinterpret_cast<const bf16x8*>(r_ + 96); } }

  // prologue queue: S0(4), A0(8), A1(8)
  STAGE_WIN(0, wbg, wbh); __builtin_amdgcn_sched_barrier(0);
  LOADW2(0); __builtin_amdgcn_sched_barrier(0);
  LOADW2(1);

  #pragma unroll
  for (int w=0; w<NWIN; ++w){
    // queue entering W_w (steady): [A(w)8, S(w)4, A(w+1)8] -> keep newest 8
    if (w < 12)       { WAITVM(8); }
    else if (w == 12) { WAITVM(4); }   // A13 is only 4 loads
    else              { WAITVM(0); }
    __builtin_amdgcn_s_barrier();

    if (w+1 < NWIN) { STAGE_WIN(w+1, wbg, wbh); }
    __builtin_amdgcn_sched_barrier(0);

    #pragma unroll
    for (int ks=0; ks<2; ks++){
      if (2*w + ks < KNBR){
        const u16* wsb = ws + (w&1)*WSU2 + ks*8192;
        #pragma unroll
        for (int tt=0;tt<2;tt++){
          bf16x8 ag = as2[w&1][ks][tt];
          bf16x8 ah = as2[w&1][ks][2+tt];
          #pragma unroll
          for (int ct=0;ct<4;ct++){
            bf16x8 bg = *reinterpret_cast<const bf16x8*>(wsb + ((tt*2+0)*4+ct)*512 + (size_t)lane*8);
            accg[ct] = __builtin_amdgcn_mfma_f32_16x16x32_bf16(ag, bg, accg[ct], 0,0,0);
          }
          #pragma unroll
          for (int ct=0;ct<4;ct++){
            bf16x8 bh = *reinterpret_cast<const bf16x8*>(wsb + ((tt*2+1)*4+ct)*512 + (size_t)lane*8);
            acch[ct] = __builtin_amdgcn_mfma_f32_16x16x32_bf16(ah, bh, acch[ct], 0,0,0);
          }
        }
      }
    }
    // A(w+2) into the slot the MFMAs above just consumed ((w+2)&1 == w&1)
    if (w+2 < NWIN) { LOADW2(w+2); }
  }

  // coupling epilogue: bg and bh live in the same wave — no LDS exchange
  #pragma unroll
  for (int ct=0;ct<4;ct++){
    #pragma unroll
    for (int i=0;i<4;i++){
      int row = row0 + wv*16 + quad*4 + i;
      if (row < NNODES){
        int col = ct*16 + m;
        float bg = accg[ct][i];
        float bh = acch[ct][i];
        float s = 1.f/(1.f + __expf(-bg));
        s = __expf(2.f*s - 1.f);
        float xv = x[(size_t)row*LDX + xcol0 + col];
        float y = xv*s + bh;
        out[(size_t)row*LDX + ycol0 + col] = y;
        if (write_yb) yb[(size_t)row*64 + col] = f2bf(y);
      }
    }
  }
  #undef LOADW2
}

extern "C" void kernel_launch(void* const* d_in, const int* in_sizes, int n_in,
                              void* d_out, int out_size, void* d_ws, size_t ws_size,
                              hipStream_t stream)
{
  const float* x   = (const float*)d_in[0];
  const int*   nbr = (const int*)d_in[1];
  const float* g1_w1=(const float*)d_in[2],  *g1_w2=(const float*)d_in[3],  *g1_w3=(const float*)d_in[4];
  const float* g2_w1=(const float*)d_in[5],  *g2_w2=(const float*)d_in[6],  *g2_w3=(const float*)d_in[7];
  const float* h1_w1=(const float*)d_in[8],  *h1_w2=(const float*)d_in[9],  *h1_w3=(const float*)d_in[10];
  const float* h2_w1=(const float*)d_in[11], *h2_w2=(const float*)d_in[12], *h2_w3=(const float*)d_in[13];
  float* out = (float*)d_out;
  u16* ws = (u16*)d_ws;

  const size_t WBB = (size_t)54*4*64*8;  // 1728-row weights (bf16 frags)
  const size_t WBS = (size_t)2*4*64*8;   // 64-row weights
  u16* p = ws;
  u16* wb_g2_1=p; p+=WBB;  u16* wb_h2_1=p; p+=WBB;
  u16* wb_g2_2=p; p+=WBS;  u16* wb_h2_2=p; p+=WBS;
  u16* wb_g2_3=p; p+=WBB;  u16* wb_h2_3=p; p+=WBB;
  u16* wb_g1_1=p; p+=WBB;  u16* wb_h1_1=p; p+=WBB;
  u16* wb_g1_2=p; p+=WBS;  u16* wb_h1_2=p; p+=WBS;
  u16* wb_g1_3=p; p+=WBB;  u16* wb_h1_3=p; p+=WBB;
  u16* ub = p; p += (size_t)NNODES*128;   // interleaved [g|h] bf16
  u16* sb = p; p += (size_t)NNODES*64;    // gather source (x2 bf16, then y1 bf16)

  reformat_w<<<54,256,0,stream>>>(g2_w1, wb_g2_1, 54);
  reformat_w<<<54,256,0,stream>>>(h2_w1, wb_h2_1, 54);
  reformat_w<<<2,256,0,stream>>>(g2_w2, wb_g2_2, 2);
  reformat_w<<<2,256,0,stream>>>(h2_w2, wb_h2_2, 2);
  reformat_w<<<54,256,0,stream>>>(g2_w3, wb_g2_3, 54);
  reformat_w<<<54,256,0,stream>>>(h2_w3, wb_h2_3, 54);
  reformat_w<<<54,256,0,stream>>>(g1_w1, wb_g1_1, 54);
  reformat_w<<<54,256,0,stream>>>(h1_w1, wb_h1_1, 54);
  reformat_w<<<2,256,0,stream>>>(g1_w2, wb_g1_2, 2);
  reformat_w<<<2,256,0,stream>>>(h1_w2, wb_h1_2, 2);
  reformat_w<<<54,256,0,stream>>>(g1_w3, wb_g1_3, 54);
  reformat_w<<<54,256,0,stream>>>(h1_w3, wb_h1_3, 54);

  conv_x2<<<(NNODES*64/8 + 255)/256, 256, 0, stream>>>(x, sb);

  int nblk = (NNODES + MR - 1)/MR;        // 1172
  size_t lds_sz = (size_t)2*WSU2*2;       // 65536 B (== 64KB limit)

  // Phase A: sb = x2(bf16); y1 -> out cols 0..63 + sb(bf16)
  conv1_fused<<<nblk,512,lds_sz,stream>>>(sb, nbr, wb_g2_1, wb_h2_1, wb_g2_2, wb_h2_2, ub);
  conv2_coupling<<<nblk,512,lds_sz,stream>>>(ub, nbr, wb_g2_3, wb_h2_3, x, 0, out, 0, sb, 1);
  // Phase B: sb = y1(bf16); y2 -> out cols 64..127
  conv1_fused<<<nblk,512,lds_sz,stream>>>(sb, nbr, wb_g1_1, wb_h1_1, wb_g1_2, wb_h1_2, ub);
  conv2_coupling<<<nblk,512,lds_sz,stream>>>(ub, nbr, wb_g1_3, wb_h1_3, x, 64, out, 64, sb, 0);
}

// Round 9
// 722.283 us; speedup vs baseline: 1.0971x; 1.0971x over previous
//
#include <hip/hip_runtime.h>
#include <stdint.h>

typedef unsigned short u16;
typedef __bf16 bf16x8 __attribute__((ext_vector_type(8)));
typedef float f32x4 __attribute__((ext_vector_type(4)));

#define NNODES 150000
#define KNBR 27
#define LDX 128
#define MR 128     // rows per block; 8 waves x 16 rows, each wave computes g AND h
#define APAD 72    // epilogue LDS row stride (u16)
#define WSU 8192   // u16 per 16KB weight stage buffer

#define WAITVM(N) asm volatile("s_waitcnt vmcnt(" #N ")" ::: "memory")

static __device__ __forceinline__ void gl_lds16(const u16* g, u16* l){
  __builtin_amdgcn_global_load_lds((const __attribute__((address_space(1))) void*)g,
                                   (__attribute__((address_space(3))) void*)l, 16, 0, 0);
}

static __device__ __forceinline__ u16 f2bf(float f){
  union { float f; uint32_t i; } v; v.f = f;
  uint32_t x = v.i;
  uint32_t r = (x + 0x7fffu + ((x >> 16) & 1u)) >> 16;  // RNE
  return (u16)r;
}
static __device__ __forceinline__ float lrelu(float v){ return v >= 0.f ? v : 0.2f*v; }

// fp32 weight (krows x 64) -> bf16 MFMA B-fragment order (one element-octet per thread)
static __device__ __forceinline__ void reformat_body(const float* __restrict__ src,
                                                     u16* __restrict__ dst, int idx){
  int lane = idx & 63;
  int ctile = (idx >> 6) & 3;
  int t = idx >> 8;
  int quad = lane >> 4, m = lane & 15;
  union { u16 h[8]; float4 v; } tmp;
  const float* s = src + ((size_t)(t*32 + quad*8))*64 + ctile*16 + m;
  #pragma unroll
  for (int j=0;j<8;j++) tmp.h[j] = f2bf(s[j*64]);
  *reinterpret_cast<float4*>(dst + (size_t)idx*8) = tmp.v;
}

// x cols 64..127 (fp32, LDX stride) -> bf16 table sb (N x 64); 8 elems per thread
static __device__ __forceinline__ void convx2_body(const float* __restrict__ x,
                                                   u16* __restrict__ sb, int idx){
  int e = idx*8;
  if (e >= NNODES*64) return;
  int row = e >> 6, col = e & 63;
  const float* s = x + (size_t)row*LDX + 64 + col;
  float4 a = *reinterpret_cast<const float4*>(s);
  float4 b = *reinterpret_cast<const float4*>(s+4);
  union { u16 h[8]; float4 v; } t;
  t.h[0]=f2bf(a.x); t.h[1]=f2bf(a.y); t.h[2]=f2bf(a.z); t.h[3]=f2bf(a.w);
  t.h[4]=f2bf(b.x); t.h[5]=f2bf(b.y); t.h[6]=f2bf(b.z); t.h[7]=f2bf(b.w);
  *reinterpret_cast<float4*>(sb + e) = t.v;
}

// One launch for all 12 weight reformats + the x2->bf16 table.
// blocks [0,432): 8 big reformats (54 blocks each); [432,440): 4 small (2 each);
// [440, 440+4688): conv_x2.
__global__ void fused_prep(
    const float* __restrict__ x, u16* __restrict__ sb,
    const float* s0, u16* d0, const float* s1, u16* d1,
    const float* s2, u16* d2, const float* s3, u16* d3,
    const float* s4, u16* d4, const float* s5, u16* d5,
    const float* s6, u16* d6, const float* s7, u16* d7,
    const float* t0, u16* e0, const float* t1, u16* e1,
    const float* t2, u16* e2, const float* t3, u16* e3)
{
  int b = blockIdx.x;
  int tid = threadIdx.x;
  if (b < 432){
    int which = b / 54;
    int idx = (b % 54)*256 + tid;          // [0, 13824) exact
    const float* s; u16* d;
    switch (which){
      case 0: s=s0; d=d0; break;  case 1: s=s1; d=d1; break;
      case 2: s=s2; d=d2; break;  case 3: s=s3; d=d3; break;
      case 4: s=s4; d=d4; break;  case 5: s=s5; d=d5; break;
      case 6: s=s6; d=d6; break;  default: s=s7; d=d7; break;
    }
    reformat_body(s, d, idx);
  } else if (b < 440){
    int which = (b - 432) >> 1;
    int idx = ((b - 432) & 1)*256 + tid;   // [0, 512) exact
    const float* s; u16* d;
    switch (which){
      case 0: s=t0; d=e0; break;  case 1: s=t1; d=e1; break;
      case 2: s=t2; d=e2; break;  default: s=t3; d=e3; break;
    }
    reformat_body(s, d, idx);
  } else {
    convx2_body(x, sb, (b - 440)*256 + tid);
  }
}

// Stage 2 of 16 weight chunks (1KB each) for k-step s into ws[s&1].
// chunk c = (tt*2+mat)*4+ct ; wave wv owns chunks 2wv, 2wv+1.
#define STAGE_W(s, wG, wH) { \
  u16* db_ = ws + ((s)&1)*WSU; \
  _Pragma("unroll") \
  for (int j_=0;j_<2;j_++){ \
    int c_ = wv*2 + j_; \
    int mat_ = (c_>>2)&1; int tt_ = c_>>3; int ct_ = c_&3; \
    const u16* src_ = (mat_ ? (wH) : (wG)) + ((size_t)(2*(s)+tt_))*2048 + (size_t)ct_*512 + (size_t)lane*8; \
    gl_lds16(src_, db_ + (size_t)c_*512); \
  } }

// u[:,0:64] = lrelu(lrelu(gather(sb) @ w1g) @ w2g); u[:,64:128] = h-version.
// 8 waves x 16 rows; each wave computes BOTH matrices.
// Weights LDS-staged (2 instr/wave/iter), single barrier/iter, counted vmcnt.
// w2 epilogue weights LDS-staged once per block.
__global__ __launch_bounds__(512,4) void conv1_fused(
    const u16* __restrict__ sb,
    const int* __restrict__ nbr,
    const u16* __restrict__ wb1g, const u16* __restrict__ wb1h,
    const u16* __restrict__ wb2g, const u16* __restrict__ wb2h,
    u16* __restrict__ u)
{
  extern __shared__ char smem[];
  u16* ws    = (u16*)smem;                    // [2][WSU] weight stages = 32768 B
  int* s_idx = (int*)(smem + 2*WSU*2);        // [MR*KNBR] = 13824 B (dies after k-loop)
  u16* sa    = (u16*)smem;                    // epilogue alias [2][MR*APAD] = 36864 B
  u16* w2l   = (u16*)(smem + 36864);          // epilogue w2 stage = 16384 B (tot 53248)

  int tid = threadIdx.x;
  int row0 = blockIdx.x * MR;
  for (int i = tid; i < MR*KNBR; i += 512){
    int r = i / KNBR, kk = i - r*KNBR;
    int row = row0 + r;
    s_idx[i] = (row < NNODES) ? nbr[row*KNBR + kk] : 0;
  }
  __syncthreads();

  int lane = tid & 63;
  int wv = tid >> 6;                          // 0..7
  int quad = lane >> 4, m = lane & 15;
  int qoff = quad * 8;
  const int* idx = &s_idx[(wv*16 + m)*KNBR];

  f32x4 acc[2][4];
  f32x4 zz = {0.f,0.f,0.f,0.f};
  #pragma unroll
  for (int mt2=0;mt2<2;mt2++)
    #pragma unroll
    for (int i=0;i<4;i++) acc[mt2][i] = zz;

  bf16x8 as[3][2];

  #define LOAD_A1(s, d0, d1) { \
    const u16* r_ = sb + (size_t)idx[s]*64 + qoff; \
    d0 = *reinterpret_cast<const bf16x8*>(r_); \
    d1 = *reinterpret_cast<const bf16x8*>(r_ + 32); }

  // prologue queue: S0(2), A0(2), A1(2), A2(2)
  STAGE_W(0, wb1g, wb1h); __builtin_amdgcn_sched_barrier(0);
  LOAD_A1(0, as[0][0], as[0][1]); __builtin_amdgcn_sched_barrier(0);
  LOAD_A1(1, as[1][0], as[1][1]); __builtin_amdgcn_sched_barrier(0);
  LOAD_A1(2, as[2][0], as[2][1]);

  #pragma unroll
  for (int k=0;k<KNBR;k++){
    // queue entering iter k (steady): [A(k+1)2, S(k)2, A(k+2)2]
    if (k == 0)       { WAITVM(4); }   // drain S0,A0; keep A1,A2
    else if (k <= 24) { WAITVM(2); }   // drain A(k+1),S(k); keep A(k+2)
    else              { WAITVM(0); }   // tail
    __builtin_amdgcn_s_barrier();      // publish S(k); buf[(k+1)&1] is free

    if (k+1 < KNBR) { STAGE_W(k+1, wb1g, wb1h); }
    __builtin_amdgcn_sched_barrier(0); // keep stage-issue ahead of compute

    const u16* wsb = ws + (k&1)*WSU;
    #pragma unroll
    for (int tt=0;tt<2;tt++){
      bf16x8 af = as[k%3][tt];
      #pragma unroll
      for (int mt2=0;mt2<2;mt2++){
        #pragma unroll
        for (int ct=0;ct<4;ct++){
          bf16x8 b = *reinterpret_cast<const bf16x8*>(wsb + ((tt*2+mt2)*4+ct)*512 + (size_t)lane*8);
          acc[mt2][ct] = __builtin_amdgcn_mfma_f32_16x16x32_bf16(af, b, acc[mt2][ct], 0,0,0);
        }
      }
    }
    // A(k+3) into the slot MFMA just consumed ((k+3)%3 == k%3)
    if (k+3 < KNBR) { LOAD_A1(k+3, as[k%3][0], as[k%3][1]); }
  }
  __syncthreads();   // all waves done with ws reads and s_idx

  // stage w2g+w2h (16KB, 16 chunks) into w2l: wave wv stages chunks 2wv,2wv+1
  #pragma unroll
  for (int j_=0;j_<2;j_++){
    int cc = wv*2 + j_;
    int mt2_ = cc>>3;                       // 0=g, 1=h
    const u16* src_ = (mt2_ ? wb2h : wb2g) + (size_t)(cc&7)*512 + (size_t)lane*8;
    gl_lds16(src_, w2l + (size_t)cc*512);
  }

  // lrelu -> bf16 tile in LDS (C-layout -> A-layout round trip); wave-private rows
  #pragma unroll
  for (int mt2=0;mt2<2;mt2++){
    #pragma unroll
    for (int ct=0;ct<4;ct++){
      #pragma unroll
      for (int i=0;i<4;i++){
        int rl = wv*16 + quad*4 + i;
        sa[mt2*MR*APAD + rl*APAD + ct*16 + m] = f2bf(lrelu(acc[mt2][ct][i]));
      }
    }
  }
  WAITVM(0);
  __syncthreads();   // w2l staged + sa visible

  f32x4 d[2][4];
  #pragma unroll
  for (int mt2=0;mt2<2;mt2++)
    #pragma unroll
    for (int i=0;i<4;i++) d[mt2][i] = zz;
  #pragma unroll
  for (int c=0;c<2;c++){
    #pragma unroll
    for (int mt2=0;mt2<2;mt2++){
      bf16x8 a = *reinterpret_cast<const bf16x8*>(&sa[mt2*MR*APAD + (wv*16 + m)*APAD + c*32 + qoff]);
      #pragma unroll
      for (int ct=0;ct<4;ct++){
        bf16x8 b = *reinterpret_cast<const bf16x8*>(w2l + (size_t)(mt2*8 + c*4 + ct)*512 + (size_t)lane*8);
        d[mt2][ct] = __builtin_amdgcn_mfma_f32_16x16x32_bf16(a, b, d[mt2][ct], 0,0,0);
      }
    }
  }
  #pragma unroll
  for (int mt2=0;mt2<2;mt2++){
    #pragma unroll
    for (int ct=0;ct<4;ct++){
      #pragma unroll
      for (int i=0;i<4;i++){
        int row = row0 + wv*16 + quad*4 + i;
        if (row < NNODES){
          u[(size_t)row*128 + mt2*64 + ct*16 + m] = f2bf(lrelu(d[mt2][ct][i]));
        }
      }
    }
  }
  #undef LOAD_A1
}

// bg = gather(u[:,:64]) @ w3g ; bh = gather(u[:,64:]) @ w3h ;
// y = x_prev * exp(2*sigmoid(bg)-1) + bh -> out fp32; optionally y -> yb bf16.
// 8 waves x 16 rows, both matrices per wave (coupling in-register).
__global__ __launch_bounds__(512,4) void conv2_coupling(
    const u16* __restrict__ ub,
    const int* __restrict__ nbr,
    const u16* __restrict__ wbg, const u16* __restrict__ wbh,
    const float* __restrict__ x, int xcol0,
    float* __restrict__ out, int ycol0,
    u16* __restrict__ yb, int write_yb)
{
  extern __shared__ char smem[];
  u16* ws    = (u16*)smem;                    // [2][WSU] = 32768 B
  int* s_idx = (int*)(smem + 2*WSU*2);        // [MR*KNBR] = 13824 B

  int tid = threadIdx.x;
  int row0 = blockIdx.x * MR;
  for (int i = tid; i < MR*KNBR; i += 512){
    int r = i / KNBR, kk = i - r*KNBR;
    int row = row0 + r;
    s_idx[i] = (row < NNODES) ? nbr[row*KNBR + kk] : 0;
  }
  __syncthreads();

  int lane = tid & 63;
  int wv = tid >> 6;                          // 0..7
  int quad = lane >> 4, m = lane & 15;
  int qoff = quad * 8;
  const int* idx = &s_idx[(wv*16 + m)*KNBR];

  f32x4 accg[4], acch[4];
  f32x4 zz = {0.f,0.f,0.f,0.f};
  #pragma unroll
  for (int i=0;i<4;i++){ accg[i]=zz; acch[i]=zz; }

  bf16x8 as[2][4];

  #define LOAD_A2(s, d0, d1, d2, d3) { \
    const u16* r_ = ub + (size_t)idx[s]*128 + qoff; \
    d0 = *reinterpret_cast<const bf16x8*>(r_); \
    d1 = *reinterpret_cast<const bf16x8*>(r_ + 32); \
    d2 = *reinterpret_cast<const bf16x8*>(r_ + 64); \
    d3 = *reinterpret_cast<const bf16x8*>(r_ + 96); }

  // prologue queue: S0(2), A0(4), A1(4)
  STAGE_W(0, wbg, wbh); __builtin_amdgcn_sched_barrier(0);
  LOAD_A2(0, as[0][0], as[0][1], as[0][2], as[0][3]); __builtin_amdgcn_sched_barrier(0);
  LOAD_A2(1, as[1][0], as[1][1], as[1][2], as[1][3]);

  #pragma unroll
  for (int k=0;k<KNBR;k++){
    // queue entering iter k (steady): [A(k)4, S(k)2, A(k+1)4]
    if (k < 26) { WAITVM(4); }   // drain A(k),S(k); keep A(k+1)
    else        { WAITVM(0); }
    __builtin_amdgcn_s_barrier();

    if (k+1 < KNBR) { STAGE_W(k+1, wbg, wbh); }
    __builtin_amdgcn_sched_barrier(0);

    const u16* wsb = ws + (k&1)*WSU;
    #pragma unroll
    for (int tt=0;tt<2;tt++){
      bf16x8 ag = as[k&1][tt];       // g cols, k-half tt
      bf16x8 ah = as[k&1][2+tt];     // h cols
      #pragma unroll
      for (int ct=0;ct<4;ct++){
        bf16x8 bg = *reinterpret_cast<const bf16x8*>(wsb + ((tt*2+0)*4+ct)*512 + (size_t)lane*8);
        accg[ct] = __builtin_amdgcn_mfma_f32_16x16x32_bf16(ag, bg, accg[ct], 0,0,0);
      }
      #pragma unroll
      for (int ct=0;ct<4;ct++){
        bf16x8 bh = *reinterpret_cast<const bf16x8*>(wsb + ((tt*2+1)*4+ct)*512 + (size_t)lane*8);
        acch[ct] = __builtin_amdgcn_mfma_f32_16x16x32_bf16(ah, bh, acch[ct], 0,0,0);
      }
    }
    // A(k+2) into the slot MFMA just consumed ((k+2)&1 == k&1)
    if (k+2 < KNBR) { LOAD_A2(k+2, as[k&1][0], as[k&1][1], as[k&1][2], as[k&1][3]); }
  }

  // coupling epilogue: bg and bh live in the same wave — no LDS exchange
  #pragma unroll
  for (int ct=0;ct<4;ct++){
    #pragma unroll
    for (int i=0;i<4;i++){
      int row = row0 + wv*16 + quad*4 + i;
      if (row < NNODES){
        int col = ct*16 + m;
        float bg = accg[ct][i];
        float bh = acch[ct][i];
        float s = 1.f/(1.f + __expf(-bg));
        s = __expf(2.f*s - 1.f);
        float xv = x[(size_t)row*LDX + xcol0 + col];
        float y = xv*s + bh;
        out[(size_t)row*LDX + ycol0 + col] = y;
        if (write_yb) yb[(size_t)row*64 + col] = f2bf(y);
      }
    }
  }
  #undef LOAD_A2
}

extern "C" void kernel_launch(void* const* d_in, const int* in_sizes, int n_in,
                              void* d_out, int out_size, void* d_ws, size_t ws_size,
                              hipStream_t stream)
{
  const float* x   = (const float*)d_in[0];
  const int*   nbr = (const int*)d_in[1];
  const float* g1_w1=(const float*)d_in[2],  *g1_w2=(const float*)d_in[3],  *g1_w3=(const float*)d_in[4];
  const float* g2_w1=(const float*)d_in[5],  *g2_w2=(const float*)d_in[6],  *g2_w3=(const float*)d_in[7];
  const float* h1_w1=(const float*)d_in[8],  *h1_w2=(const float*)d_in[9],  *h1_w3=(const float*)d_in[10];
  const float* h2_w1=(const float*)d_in[11], *h2_w2=(const float*)d_in[12], *h2_w3=(const float*)d_in[13];
  float* out = (float*)d_out;
  u16* ws = (u16*)d_ws;

  const size_t WBB = (size_t)54*4*64*8;  // 1728-row weights (bf16 frags)
  const size_t WBS = (size_t)2*4*64*8;   // 64-row weights
  u16* p = ws;
  u16* wb_g2_1=p; p+=WBB;  u16* wb_h2_1=p; p+=WBB;
  u16* wb_g2_2=p; p+=WBS;  u16* wb_h2_2=p; p+=WBS;
  u16* wb_g2_3=p; p+=WBB;  u16* wb_h2_3=p; p+=WBB;
  u16* wb_g1_1=p; p+=WBB;  u16* wb_h1_1=p; p+=WBB;
  u16* wb_g1_2=p; p+=WBS;  u16* wb_h1_2=p; p+=WBS;
  u16* wb_g1_3=p; p+=WBB;  u16* wb_h1_3=p; p+=WBB;
  u16* ub = p; p += (size_t)NNODES*128;   // interleaved [g|h] bf16
  u16* sb = p; p += (size_t)NNODES*64;    // gather source (x2 bf16, then y1 bf16)

  // one launch for all 12 reformats + conv_x2 (blocks: 8*54 + 4*2 + 4688)
  int prep_blocks = 432 + 8 + (NNODES*64/8 + 255)/256;
  fused_prep<<<prep_blocks,256,0,stream>>>(
      x, sb,
      g2_w1, wb_g2_1,  h2_w1, wb_h2_1,  g2_w3, wb_g2_3,  h2_w3, wb_h2_3,
      g1_w1, wb_g1_1,  h1_w1, wb_h1_1,  g1_w3, wb_g1_3,  h1_w3, wb_h1_3,
      g2_w2, wb_g2_2,  h2_w2, wb_h2_2,  g1_w2, wb_g1_2,  h1_w2, wb_h1_2);

  int nblk = (NNODES + MR - 1)/MR;        // 1172
  size_t c1_lds = 53248;                  // ws 32K + s_idx 13.8K; epi: sa 36K + w2l 16K
  size_t c2_lds = (size_t)2*WSU*2 + (size_t)MR*KNBR*4;  // 46592 B

  // Phase A: sb = x2(bf16); y1 -> out cols 0..63 + sb(bf16)
  conv1_fused<<<nblk,512,c1_lds,stream>>>(sb, nbr, wb_g2_1, wb_h2_1, wb_g2_2, wb_h2_2, ub);
  conv2_coupling<<<nblk,512,c2_lds,stream>>>(ub, nbr, wb_g2_3, wb_h2_3, x, 0, out, 0, sb, 1);
  // Phase B: sb = y1(bf16); y2 -> out cols 64..127
  conv1_fused<<<nblk,512,c1_lds,stream>>>(sb, nbr, wb_g1_1, wb_h1_1, wb_g1_2, wb_h1_2, ub);
  conv2_coupling<<<nblk,512,c2_lds,stream>>>(ub, nbr, wb_g1_3, wb_h1_3, x, 64, out, 64, sb, 0);
}